// Round 4
// baseline (251.369 us; speedup 1.0000x reference)
//
#include <hip/hip_runtime.h>
#include <hip/hip_bf16.h>
#include <math.h>

#define CDIM 192
#define NHEADS 6
#define WIN 7
#define KWIN 49
#define BATCH 4
#define PIX 3136      // 56*56
#define NPIX 12544    // BATCH*PIX
#define NIMG 24       // BATCH*NHEADS
#define EPSV 1e-5f

typedef __bf16 bf16x8 __attribute__((ext_vector_type(8)));
typedef float f32x16 __attribute__((ext_vector_type(16)));
typedef unsigned int uint4v __attribute__((ext_vector_type(4)));
typedef unsigned short u16;

// ---------------- BN stats ---------------------------------------------------
__global__ __launch_bounds__(256) void bn_stats_k(const float* __restrict__ x,
                                                  float* __restrict__ stats) {
  int c = blockIdx.x;
  float s = 0.f, q = 0.f;
  for (int n = threadIdx.x; n < BATCH * PIX; n += 256) {
    int b = n / PIX, p = n - b * PIX;
    float v = x[((size_t)b * CDIM + c) * PIX + p];
    s += v; q += v * v;
  }
  __shared__ float rs[256], rq[256];
  rs[threadIdx.x] = s; rq[threadIdx.x] = q;
  __syncthreads();
  for (int st = 128; st > 0; st >>= 1) {
    if (threadIdx.x < st) { rs[threadIdx.x] += rs[threadIdx.x + st]; rq[threadIdx.x] += rq[threadIdx.x + st]; }
    __syncthreads();
  }
  if (threadIdx.x == 0) {
    float mean = rs[0] / (float)(BATCH * PIX);
    float var = rq[0] / (float)(BATCH * PIX) - mean * mean;
    stats[c] = mean;
    stats[CDIM + c] = rsqrtf(var + EPSV);
  }
}

// ---------------- fold BN + q-scale into qkv weights ------------------------
__global__ __launch_bounds__(192) void fold_k(const float* __restrict__ qkv_w,
                                              const float* __restrict__ qkv_b,
                                              const float* __restrict__ gamma,
                                              const float* __restrict__ beta,
                                              const float* __restrict__ stats,
                                              float* __restrict__ w_eff,
                                              float* __restrict__ b_eff) {
  int o = blockIdx.x, c = threadIdx.x;
  float alpha = gamma[c] * stats[CDIM + c];
  float shift = beta[c] - stats[c] * alpha;
  float w = qkv_w[o * CDIM + c];
  float scale = (o < CDIM) ? 0.17677669529663687f : 1.f;
  w_eff[o * CDIM + c] = w * alpha * scale;
  __shared__ float r[CDIM];
  r[c] = w * shift;
  __syncthreads();
  if (c == 0) {
    float s = 0.f;
    for (int i = 0; i < CDIM; i++) s += r[i];
    b_eff[o] = (qkv_b[o] + s) * scale;
  }
}

// ---------------- pack dm_w (attn conv weights) frag-major ------------------
__global__ __launch_bounds__(256) void wprep_k(const float* __restrict__ dm_w,
                                               __hip_bfloat16* __restrict__ wTb2) {
  int idx = blockIdx.x * 256 + threadIdx.x;
  if (idx >= 200704) return;
  int e = idx & 7;
  int tmp = idx >> 3;
  int lane = tmp & 63; tmp >>= 6;
  int ch = tmp & 3; tmp >>= 2;
  int tap = tmp % 49, Mt = tmp / 49;
  int ko = Mt * 32 + (lane & 31);
  int ci = ch * 16 + (lane >> 5) * 8 + e;
  float v = (ko < KWIN) ? dm_w[(size_t)ko * 3136 + ci * 49 + tap] : 0.f;
  wTb2[idx] = __float2bfloat16(v);
}

// ---------------- generic GEMM weight pack: W[Cout][Cin] -> frag-major ------
__global__ __launch_bounds__(256) void pack_k(const float* __restrict__ W,
                                              u16* __restrict__ out,
                                              int Cin, int total8) {
  int t = blockIdx.x * 256 + threadIdx.x;
  if (t >= total8) return;
  int lane = t & 63, rest = t >> 6;
  int nK = Cin >> 4;
  int kk = rest % nK, mtg = rest / nK;
  int o = mtg * 32 + (lane & 31), c = kk * 16 + (lane >> 5) * 8;
  const float* src = W + (size_t)o * Cin + c;
  __hip_bfloat16 tmp[8];
#pragma unroll
  for (int e = 0; e < 8; e++) tmp[e] = __float2bfloat16(src[e]);
  *(uint4v*)(out + (size_t)t * 8) = *(uint4v*)tmp;
}

// ---------------- x [b][c][p] fp32 -> xT [b*p][192] bf16 --------------------
__global__ __launch_bounds__(256) void xT_k(const float* __restrict__ x,
                                            u16* __restrict__ xT) {
  __shared__ float Ls[64][33];
  int bb = blockIdx.x / 49;
  int p0 = (blockIdx.x % 49) * 64;
  int c0 = blockIdx.y * 32;
  int tid = threadIdx.x;
  int j = tid & 63;
#pragma unroll
  for (int it = 0; it < 8; it++) {
    int c = it * 4 + (tid >> 6);
    Ls[j][c] = x[((size_t)bb * CDIM + c0 + c) * PIX + p0 + j];
  }
  __syncthreads();
  int jr = tid >> 2, t = tid & 3;
  __hip_bfloat16 tmp[8];
#pragma unroll
  for (int u = 0; u < 8; u++) tmp[u] = __float2bfloat16(Ls[jr][t * 8 + u]);
  *(uint4v*)(xT + (size_t)(bb * PIX + p0 + jr) * CDIM + c0 + t * 8) = *(uint4v*)tmp;
}

// ---------------- MFMA GEMM: Y[o][gp] = sum_c W[o][c] * Bm[gp][c] -----------
// Bm: [NPIX][Cin] bf16 pixel-major. Apk: frag-major packed weights.
// Bs layout: granule-major [g][256 px] 16B slots -> conflict-free ds_read_b128.
#define MG_QKV 0
#define MG_PROJ 1
#define MG_GELU 2
#define MG_C2 3

template <int EPI>
__global__ __launch_bounds__(256) void mgemm_k(
    const u16* __restrict__ Bm, const u16* __restrict__ Apk,
    const float* __restrict__ bias,
    float* __restrict__ outF, u16* __restrict__ outT,
    const float* __restrict__ extra, int Cin) {
  __shared__ __align__(16) u16 Bs[256 * 64];  // 32 KB
  int tid = threadIdx.x;
  int lane = tid & 63, wid = tid >> 6;
  int hi = lane >> 5, ln31 = lane & 31;
  int p0 = blockIdx.x * 256;
  int o0 = blockIdx.y * 64;
  int nK = Cin >> 4;
  f32x16 acc[2][2];
#pragma unroll
  for (int mt = 0; mt < 2; mt++)
#pragma unroll
    for (int nt = 0; nt < 2; nt++)
#pragma unroll
      for (int i = 0; i < 16; i++) acc[mt][nt][i] = 0.f;

  for (int cc = 0; cc < Cin; cc += 64) {
#pragma unroll
    for (int i = 0; i < 8; i++) {
      int idx = i * 256 + tid;
      int p = idx & 255, g = idx >> 8;
      uint4v v = *(const uint4v*)(Bm + (size_t)(p0 + p) * Cin + cc + g * 8);
      *(uint4v*)&Bs[g * 2048 + p * 8] = v;
    }
    __syncthreads();
    const u16* Ab = Apk + ((size_t)(o0 >> 5) * nK + (cc >> 4)) * 512 + lane * 8;
    int pA = wid * 64 + ln31;
    int pB = pA + 32;
#pragma unroll
    for (int ks = 0; ks < 4; ks++) {
      int g = ks * 2 + hi;
      bf16x8 b0 = *(const bf16x8*)&Bs[g * 2048 + pA * 8];
      bf16x8 b1 = *(const bf16x8*)&Bs[g * 2048 + pB * 8];
      bf16x8 a0 = *(const bf16x8*)(Ab + ks * 512);
      bf16x8 a1 = *(const bf16x8*)(Ab + (nK + ks) * 512);
      acc[0][0] = __builtin_amdgcn_mfma_f32_32x32x16_bf16(a0, b0, acc[0][0], 0, 0, 0);
      acc[0][1] = __builtin_amdgcn_mfma_f32_32x32x16_bf16(a0, b1, acc[0][1], 0, 0, 0);
      acc[1][0] = __builtin_amdgcn_mfma_f32_32x32x16_bf16(a1, b0, acc[1][0], 0, 0, 0);
      acc[1][1] = __builtin_amdgcn_mfma_f32_32x32x16_bf16(a1, b1, acc[1][1], 0, 0, 0);
    }
    __syncthreads();
  }

  // ---- epilogue ----
  if (EPI == MG_C2 || (EPI == MG_QKV && o0 >= 384)) {
#pragma unroll
    for (int mt = 0; mt < 2; mt++)
#pragma unroll
      for (int r = 0; r < 16; r++) {
        int o = o0 + mt * 32 + (r & 3) + 8 * (r >> 2) + 4 * hi;
        float bv = bias[o];
#pragma unroll
        for (int nt = 0; nt < 2; nt++) {
          unsigned gp = p0 + wid * 64 + nt * 32 + ln31;
          unsigned bb = gp / PIX, pp = gp - bb * PIX;
          if (EPI == MG_C2) {
            size_t oi = ((size_t)bb * CDIM + o) * PIX + pp;
            outF[oi] = acc[mt][nt][r] + bv + extra[oi];
          } else {  // v
            int ch = o - 384;
            outF[((size_t)(bb * NHEADS + (ch >> 5)) * 32 + (ch & 31)) * PIX + pp] =
                acc[mt][nt][r] + bv;
          }
        }
      }
  } else {
    // bf16-transposed output via wave-local LDS transpose (Bs reused as scratch)
#pragma unroll
    for (int mt = 0; mt < 2; mt++)
#pragma unroll
      for (int r = 0; r < 16; r++) {
        int o_loc = mt * 32 + (r & 3) + 8 * (r >> 2) + 4 * hi;
        int o = o0 + o_loc;
        float bv = bias[o];
#pragma unroll
        for (int nt = 0; nt < 2; nt++) {
          int p_loc = wid * 64 + nt * 32 + ln31;
          float val = acc[mt][nt][r] + bv;
          if (EPI == MG_PROJ) {
            unsigned gp = p0 + p_loc;
            unsigned bb = gp / PIX, pp = gp - bb * PIX;
            size_t oi = ((size_t)bb * CDIM + o) * PIX + pp;
            val += extra[oi];
            outF[oi] = val;
          }
          if (EPI == MG_GELU)
            val = 0.5f * val * (1.f + erff(val * 0.70710678118654752f));
          *(__hip_bfloat16*)&Bs[p_loc * 64 + (((o_loc >> 3) ^ (p_loc & 7)) << 3) + (o_loc & 7)] =
              __float2bfloat16(val);
        }
      }
    int prow = wid * 64 + lane;
    int psw = prow & 7;
    uint4v r8[8];
#pragma unroll
    for (int g = 0; g < 8; g++)
      r8[g] = *(const uint4v*)&Bs[prow * 64 + ((g ^ psw) << 3)];
    unsigned gp = p0 + prow;
    if (EPI == MG_QKV) {
      unsigned bb = gp / PIX, pp = gp - bb * PIX;
      int s = (o0 >= 192) ? 1 : 0;
      int h0 = (o0 - s * 192) >> 5;
      u16* d0 = outT + ((size_t)(bb * NHEADS + h0) * PIX + pp) * 64 + s * 32;
      u16* d1 = outT + ((size_t)(bb * NHEADS + h0 + 1) * PIX + pp) * 64 + s * 32;
      *(uint4v*)(d0) = r8[0]; *(uint4v*)(d0 + 8) = r8[1];
      *(uint4v*)(d0 + 16) = r8[2]; *(uint4v*)(d0 + 24) = r8[3];
      *(uint4v*)(d1) = r8[4]; *(uint4v*)(d1 + 8) = r8[5];
      *(uint4v*)(d1 + 16) = r8[6]; *(uint4v*)(d1 + 24) = r8[7];
    } else if (EPI == MG_PROJ) {
      u16* d = outT + (size_t)gp * CDIM + o0;
#pragma unroll
      for (int g = 0; g < 8; g++) *(uint4v*)(d + g * 8) = r8[g];
    } else {  // GELU -> hT [gp][768]
      u16* d = outT + (size_t)gp * 768 + o0;
#pragma unroll
      for (int g = 0; g < 8; g++) *(uint4v*)(d + g * 8) = r8[g];
    }
  }
}

// ---------------- 7x7 attn conv: img-batched implicit-GEMM MFMA -------------
// Block = (tile, 3-image group). 6 waves: wave = (im_local, Ntile).
// LDS: 3 patches, granule-major [im][g(8)][lp(196)] 16B slots (conflict-free).
// Each wave holds both ko-Mtiles in regs: A reused 6x (2 Mt x 3 img) per load.
__global__ __launch_bounds__(384, 3) void attn_mfma_k(
    const u16* __restrict__ qkT, const u16* __restrict__ wTb2,
    const float* __restrict__ dm_b, const float* __restrict__ rel_bias,
    float* __restrict__ attnL) {
  __shared__ __align__(16) u16 patch[3 * 12544];  // 75 KB
  int tile = blockIdx.x % 49;
  int grp = blockIdx.x / 49;
  int y0 = (tile / 7) * 8, x0 = (tile % 7) * 8;
  int tid = threadIdx.x;

  // stage 3 patches, lp-major lanes (consecutive lanes -> consecutive slots)
  for (int idx = tid; idx < 4704; idx += 384) {
    int im = idx / 1568, r1 = idx - im * 1568;
    int g = r1 / 196, lp = r1 - g * 196;
    int row = lp / 14, col = lp - row * 14;
    int gy = y0 - 3 + row, gx = x0 - 3 + col;
    uint4v val = {0u, 0u, 0u, 0u};
    if ((unsigned)gy < 56u && (unsigned)gx < 56u)
      val = *(const uint4v*)(qkT + ((size_t)(grp * 3 + im) * PIX + gy * 56 + gx) * 64 + g * 8);
    *(uint4v*)&patch[idx * 8] = val;
  }
  __syncthreads();

  int lane = tid & 63, wid = tid >> 6;
  int im_local = wid >> 1, Nt = wid & 1;
  int n = lane & 31, kgrp = lane >> 5;
  int py = Nt * 4 + (n >> 3), px = n & 7;
  int pbase = im_local * 12544 + kgrp * 1568;
  f32x16 acc[2];
#pragma unroll
  for (int mt = 0; mt < 2; mt++)
#pragma unroll
    for (int i = 0; i < 16; i++) acc[mt][i] = 0.f;

  const u16* Ab = wTb2 + lane * 8;
#pragma unroll
  for (int kh = 0; kh < 7; kh++) {
#pragma unroll
    for (int kw = 0; kw < 7; kw++) {
      int tap = kh * 7 + kw;
      int lp8 = pbase + ((py + kh) * 14 + px + kw) * 8;
      const u16* Af = Ab + (size_t)tap * 2048;
#pragma unroll
      for (int ks = 0; ks < 4; ks++) {
        bf16x8 a0 = __builtin_bit_cast(bf16x8, *(const uint4v*)(Af + ks * 512));
        bf16x8 a1 = __builtin_bit_cast(bf16x8, *(const uint4v*)(Af + 100352 + ks * 512));
        bf16x8 bb = __builtin_bit_cast(bf16x8, *(const uint4v*)&patch[lp8 + ks * 3136]);
        acc[0] = __builtin_amdgcn_mfma_f32_32x32x16_bf16(a0, bb, acc[0], 0, 0, 0);
        acc[1] = __builtin_amdgcn_mfma_f32_32x32x16_bf16(a1, bb, acc[1], 0, 0, 0);
      }
    }
  }

  int img = grp * 3 + im_local;
  int head = img % NHEADS;
  int pout = (y0 + py) * 56 + x0 + px;
  float* outb = attnL + (size_t)img * KWIN * PIX + pout;
#pragma unroll
  for (int mt = 0; mt < 2; mt++)
#pragma unroll
    for (int r = 0; r < 16; r++) {
      int ko = mt * 32 + (r & 3) + 8 * (r >> 2) + 4 * kgrp;
      if (ko < KWIN)
        outb[(size_t)ko * PIX] = acc[mt][r] + dm_b[ko] + rel_bias[ko * NHEADS + head];
    }
}

// ---------------- softmax(49) + v-patch aggregation -> attnoT bf16 ----------
__global__ __launch_bounds__(256) void softagg_k(const float* __restrict__ attnL,
                                                 const float* __restrict__ v,
                                                 u16* __restrict__ attnoT) {
  __shared__ float vp[32][196];
  int img = blockIdx.x / 49, tile = blockIdx.x % 49;
  int y0 = (tile / 7) * 8, x0 = (tile % 7) * 8;
  int tid = threadIdx.x;
  const float* vi = v + (size_t)img * 32 * PIX;
  for (int idx = tid; idx < 32 * 196; idx += 256) {
    int ch = idx / 196, rr = idx - ch * 196;
    int r = rr / 14, cc2 = rr - r * 14;
    int gy = y0 - 3 + r, gx = x0 - 3 + cc2;
    vp[ch][rr] = ((unsigned)gy < 56u && (unsigned)gx < 56u)
                     ? vi[(size_t)ch * PIX + gy * 56 + gx] : 0.f;
  }
  __syncthreads();
  int px = tid & 7, py = (tid >> 3) & 7, cq = tid >> 6;
  int p = (y0 + py) * 56 + x0 + px;
  const float* al = attnL + (size_t)img * KWIN * PIX + p;
  float a[49];
  float m = -1e30f;
#pragma unroll
  for (int k = 0; k < KWIN; k++) { a[k] = al[(size_t)k * PIX]; m = fmaxf(m, a[k]); }
  float s = 0.f;
#pragma unroll
  for (int k = 0; k < KWIN; k++) { a[k] = __expf(a[k] - m); s += a[k]; }
  float inv = 1.f / s;
  int b = img / NHEADS, head = img % NHEADS;
  __hip_bfloat16 ob[8];
#pragma unroll
  for (int c8 = 0; c8 < 8; c8++) {
    int c = cq * 8 + c8;
    float accv = 0.f;
#pragma unroll
    for (int kh = 0; kh < 7; kh++)
#pragma unroll
      for (int kw = 0; kw < 7; kw++)
        accv += a[kh * 7 + kw] * vp[c][(py + kh) * 14 + px + kw];
    ob[c8] = __float2bfloat16(accv * inv);
  }
  *(uint4v*)(attnoT + ((size_t)b * PIX + p) * CDIM + head * 32 + cq * 8) = *(uint4v*)ob;
}

// ---------------- launch ----------------------------------------------------
extern "C" void kernel_launch(void* const* d_in, const int* in_sizes, int n_in,
                              void* d_out, int out_size, void* d_ws, size_t ws_size,
                              hipStream_t stream) {
  const float* x        = (const float*)d_in[0];
  const float* bn_gamma = (const float*)d_in[1];
  const float* bn_beta  = (const float*)d_in[2];
  const float* qkv_w    = (const float*)d_in[3];
  const float* qkv_b    = (const float*)d_in[4];
  const float* dm_w     = (const float*)d_in[5];
  const float* dm_b     = (const float*)d_in[6];
  const float* rel_bias = (const float*)d_in[7];
  const float* proj_w   = (const float*)d_in[8];
  const float* proj_b   = (const float*)d_in[9];
  const float* c1_w     = (const float*)d_in[10];
  const float* c1_b     = (const float*)d_in[11];
  const float* c2_w     = (const float*)d_in[12];
  const float* c2_b     = (const float*)d_in[13];
  float* out = (float*)d_out;
  float* ws  = (float*)d_ws;

  float* stats   = ws;
  float* w_eff   = stats + 384;
  float* b_eff   = w_eff + 110592;
  u16*   pk_qkv  = (u16*)(b_eff + 576);      // 110592 u16
  u16*   pk_proj = pk_qkv + 110592;          // 36864
  u16*   pk_c1   = pk_proj + 36864;          // 147456
  u16*   pk_c2   = pk_c1 + 147456;           // 147456
  u16*   wTb2    = pk_c2 + 147456;           // 200704
  u16*   xT      = wTb2 + 200704;            // 2408448 u16
  u16*   qkT     = xT + 2408448;             // 4816896 u16
  float* vbuf    = (float*)(qkT + 4816896);  // 2408448 f
  float* attnL   = vbuf + 2408448;           // 3687936 f
  u16*   attnoT  = (u16*)(attnL + 3687936);  // 2408448 u16
  float* x1      = (float*)(attnoT + 2408448);  // 2408448 f
  u16*   x1T     = (u16*)(x1 + 2408448);     // 2408448 u16
  u16*   hT      = xT;  // alias: 9633792 u16 over dead xT+qkT+vbuf (12M u16)

  bn_stats_k<<<CDIM, 256, 0, stream>>>(x, stats);
  fold_k<<<576, 192, 0, stream>>>(qkv_w, qkv_b, bn_gamma, bn_beta, stats, w_eff, b_eff);
  wprep_k<<<784, 256, 0, stream>>>(dm_w, (__hip_bfloat16*)wTb2);
  pack_k<<<54, 256, 0, stream>>>(w_eff, pk_qkv, 192, 13824);
  pack_k<<<18, 256, 0, stream>>>(proj_w, pk_proj, 192, 4608);
  pack_k<<<72, 256, 0, stream>>>(c1_w, pk_c1, 192, 18432);
  pack_k<<<72, 256, 0, stream>>>(c2_w, pk_c2, 768, 18432);
  xT_k<<<dim3(BATCH * 49, 6), 256, 0, stream>>>(x, xT);

  mgemm_k<MG_QKV><<<dim3(49, 9), 256, 0, stream>>>(
      xT, pk_qkv, b_eff, vbuf, qkT, nullptr, 192);
  attn_mfma_k<<<392, 384, 0, stream>>>(qkT, wTb2, dm_b, rel_bias, attnL);
  softagg_k<<<NIMG * 49, 256, 0, stream>>>(attnL, vbuf, attnoT);
  mgemm_k<MG_PROJ><<<dim3(49, 3), 256, 0, stream>>>(
      attnoT, pk_proj, proj_b, x1, x1T, x, 192);
  mgemm_k<MG_GELU><<<dim3(49, 12), 256, 0, stream>>>(
      x1T, pk_c1, c1_b, nullptr, hT, nullptr, 192);
  mgemm_k<MG_C2><<<dim3(49, 3), 256, 0, stream>>>(
      hT, pk_c2, c2_b, out, nullptr, x1, 768);
}

// Round 5
// 197.942 us; speedup vs baseline: 1.2699x; 1.2699x over previous
//
#include <hip/hip_runtime.h>
#include <hip/hip_bf16.h>
#include <math.h>

#define CDIM 192
#define NHEADS 6
#define WIN 7
#define KWIN 49
#define BATCH 4
#define PIX 3136      // 56*56
#define NPIX 12544    // BATCH*PIX
#define NIMG 24       // BATCH*NHEADS
#define EPSV 1e-5f

typedef __bf16 bf16x8 __attribute__((ext_vector_type(8)));
typedef float f32x16 __attribute__((ext_vector_type(16)));
typedef unsigned int uint4v __attribute__((ext_vector_type(4)));
typedef unsigned short u16;

// ---------------- BN stats ---------------------------------------------------
__global__ __launch_bounds__(256) void bn_stats_k(const float* __restrict__ x,
                                                  float* __restrict__ stats) {
  int c = blockIdx.x;
  float s = 0.f, q = 0.f;
  for (int n = threadIdx.x; n < BATCH * PIX; n += 256) {
    int b = n / PIX, p = n - b * PIX;
    float v = x[((size_t)b * CDIM + c) * PIX + p];
    s += v; q += v * v;
  }
  __shared__ float rs[256], rq[256];
  rs[threadIdx.x] = s; rq[threadIdx.x] = q;
  __syncthreads();
  for (int st = 128; st > 0; st >>= 1) {
    if (threadIdx.x < st) { rs[threadIdx.x] += rs[threadIdx.x + st]; rq[threadIdx.x] += rq[threadIdx.x + st]; }
    __syncthreads();
  }
  if (threadIdx.x == 0) {
    float mean = rs[0] / (float)(BATCH * PIX);
    float var = rq[0] / (float)(BATCH * PIX) - mean * mean;
    stats[c] = mean;
    stats[CDIM + c] = rsqrtf(var + EPSV);
  }
}

// ---------------- fold BN + q-scale into qkv weights ------------------------
__global__ __launch_bounds__(192) void fold_k(const float* __restrict__ qkv_w,
                                              const float* __restrict__ qkv_b,
                                              const float* __restrict__ gamma,
                                              const float* __restrict__ beta,
                                              const float* __restrict__ stats,
                                              float* __restrict__ w_eff,
                                              float* __restrict__ b_eff) {
  int o = blockIdx.x, c = threadIdx.x;
  float alpha = gamma[c] * stats[CDIM + c];
  float shift = beta[c] - stats[c] * alpha;
  float w = qkv_w[o * CDIM + c];
  float scale = (o < CDIM) ? 0.17677669529663687f : 1.f;
  w_eff[o * CDIM + c] = w * alpha * scale;
  __shared__ float r[CDIM];
  r[c] = w * shift;
  __syncthreads();
  if (c == 0) {
    float s = 0.f;
    for (int i = 0; i < CDIM; i++) s += r[i];
    b_eff[o] = (qkv_b[o] + s) * scale;
  }
}

// ---------------- pack dm_w (attn conv weights) frag-major ------------------
__global__ __launch_bounds__(256) void wprep_k(const float* __restrict__ dm_w,
                                               __hip_bfloat16* __restrict__ wTb2) {
  int idx = blockIdx.x * 256 + threadIdx.x;
  if (idx >= 200704) return;
  int e = idx & 7;
  int tmp = idx >> 3;
  int lane = tmp & 63; tmp >>= 6;
  int ch = tmp & 3; tmp >>= 2;
  int tap = tmp % 49, Mt = tmp / 49;
  int ko = Mt * 32 + (lane & 31);
  int ci = ch * 16 + (lane >> 5) * 8 + e;
  float v = (ko < KWIN) ? dm_w[(size_t)ko * 3136 + ci * 49 + tap] : 0.f;
  wTb2[idx] = __float2bfloat16(v);
}

// ---------------- generic GEMM weight pack: W[Cout][Cin] -> frag-major ------
__global__ __launch_bounds__(256) void pack_k(const float* __restrict__ W,
                                              u16* __restrict__ out,
                                              int Cin, int total8) {
  int t = blockIdx.x * 256 + threadIdx.x;
  if (t >= total8) return;
  int lane = t & 63, rest = t >> 6;
  int nK = Cin >> 4;
  int kk = rest % nK, mtg = rest / nK;
  int o = mtg * 32 + (lane & 31), c = kk * 16 + (lane >> 5) * 8;
  const float* src = W + (size_t)o * Cin + c;
  __hip_bfloat16 tmp[8];
#pragma unroll
  for (int e = 0; e < 8; e++) tmp[e] = __float2bfloat16(src[e]);
  *(uint4v*)(out + (size_t)t * 8) = *(uint4v*)tmp;
}

// ---------------- x [b][c][p] fp32 -> xT [b*p][192] bf16 --------------------
__global__ __launch_bounds__(256) void xT_k(const float* __restrict__ x,
                                            u16* __restrict__ xT) {
  __shared__ float Ls[64][33];
  int bb = blockIdx.x / 49;
  int p0 = (blockIdx.x % 49) * 64;
  int c0 = blockIdx.y * 32;
  int tid = threadIdx.x;
  int j = tid & 63;
#pragma unroll
  for (int it = 0; it < 8; it++) {
    int c = it * 4 + (tid >> 6);
    Ls[j][c] = x[((size_t)bb * CDIM + c0 + c) * PIX + p0 + j];
  }
  __syncthreads();
  int jr = tid >> 2, t = tid & 3;
  __hip_bfloat16 tmp[8];
#pragma unroll
  for (int u = 0; u < 8; u++) tmp[u] = __float2bfloat16(Ls[jr][t * 8 + u]);
  *(uint4v*)(xT + (size_t)(bb * PIX + p0 + jr) * CDIM + c0 + t * 8) = *(uint4v*)tmp;
}

// ---------------- MFMA GEMM: Y[o][gp] = sum_c W[o][c] * Bm[gp][c] -----------
// Bs layout: granule-major [g][p], granule stride 2056 u16 (pad: writes spread
// over 8 distinct 16B slots, reads uniform). Staging g-minor => coalesced 128B.
#define MG_QKV 0
#define MG_PROJ 1
#define MG_GELU 2
#define MG_C2 3
#define MGS 2056

template <int EPI>
__global__ __launch_bounds__(256) void mgemm_k(
    const u16* __restrict__ Bm, const u16* __restrict__ Apk,
    const float* __restrict__ bias,
    float* __restrict__ outF, u16* __restrict__ outT,
    const float* __restrict__ extra, int Cin) {
  __shared__ __align__(16) u16 Bs[8 * MGS];  // 32.9 KB
  int tid = threadIdx.x;
  int lane = tid & 63, wid = tid >> 6;
  int hi = lane >> 5, ln31 = lane & 31;
  int p0 = blockIdx.x * 256;
  int o0 = blockIdx.y * 64;
  int nK = Cin >> 4;
  f32x16 acc[2][2];
#pragma unroll
  for (int mt = 0; mt < 2; mt++)
#pragma unroll
    for (int nt = 0; nt < 2; nt++)
#pragma unroll
      for (int i = 0; i < 16; i++) acc[mt][nt][i] = 0.f;

  for (int cc = 0; cc < Cin; cc += 64) {
#pragma unroll
    for (int i = 0; i < 8; i++) {
      int idx = i * 256 + tid;
      int g = idx & 7, p = idx >> 3;
      uint4v v = *(const uint4v*)(Bm + (size_t)(p0 + p) * Cin + cc + g * 8);
      *(uint4v*)&Bs[g * MGS + p * 8] = v;
    }
    __syncthreads();
    const u16* Ab = Apk + ((size_t)(o0 >> 5) * nK + (cc >> 4)) * 512 + lane * 8;
    int pA = wid * 64 + ln31;
    int pB = pA + 32;
#pragma unroll
    for (int ks = 0; ks < 4; ks++) {
      int g = ks * 2 + hi;
      bf16x8 b0 = *(const bf16x8*)&Bs[g * MGS + pA * 8];
      bf16x8 b1 = *(const bf16x8*)&Bs[g * MGS + pB * 8];
      bf16x8 a0 = *(const bf16x8*)(Ab + ks * 512);
      bf16x8 a1 = *(const bf16x8*)(Ab + (nK + ks) * 512);
      acc[0][0] = __builtin_amdgcn_mfma_f32_32x32x16_bf16(a0, b0, acc[0][0], 0, 0, 0);
      acc[0][1] = __builtin_amdgcn_mfma_f32_32x32x16_bf16(a0, b1, acc[0][1], 0, 0, 0);
      acc[1][0] = __builtin_amdgcn_mfma_f32_32x32x16_bf16(a1, b0, acc[1][0], 0, 0, 0);
      acc[1][1] = __builtin_amdgcn_mfma_f32_32x32x16_bf16(a1, b1, acc[1][1], 0, 0, 0);
    }
    __syncthreads();
  }

  // ---- epilogue ----
  if (EPI == MG_C2 || (EPI == MG_QKV && o0 >= 384)) {
#pragma unroll
    for (int mt = 0; mt < 2; mt++)
#pragma unroll
      for (int r = 0; r < 16; r++) {
        int o = o0 + mt * 32 + (r & 3) + 8 * (r >> 2) + 4 * hi;
        float bv = bias[o];
#pragma unroll
        for (int nt = 0; nt < 2; nt++) {
          unsigned gp = p0 + wid * 64 + nt * 32 + ln31;
          unsigned bb = gp / PIX, pp = gp - bb * PIX;
          if (EPI == MG_C2) {
            size_t oi = ((size_t)bb * CDIM + o) * PIX + pp;
            outF[oi] = acc[mt][nt][r] + bv + extra[oi];
          } else {  // v
            int ch = o - 384;
            outF[((size_t)(bb * NHEADS + (ch >> 5)) * 32 + (ch & 31)) * PIX + pp] =
                acc[mt][nt][r] + bv;
          }
        }
      }
  } else {
    // bf16-transposed output via wave-local LDS transpose (Bs reused as scratch)
#pragma unroll
    for (int mt = 0; mt < 2; mt++)
#pragma unroll
      for (int r = 0; r < 16; r++) {
        int o_loc = mt * 32 + (r & 3) + 8 * (r >> 2) + 4 * hi;
        int o = o0 + o_loc;
        float bv = bias[o];
#pragma unroll
        for (int nt = 0; nt < 2; nt++) {
          int p_loc = wid * 64 + nt * 32 + ln31;
          float val = acc[mt][nt][r] + bv;
          if (EPI == MG_PROJ) {
            unsigned gp = p0 + p_loc;
            unsigned bb = gp / PIX, pp = gp - bb * PIX;
            size_t oi = ((size_t)bb * CDIM + o) * PIX + pp;
            val += extra[oi];
            outF[oi] = val;
          }
          if (EPI == MG_GELU)
            val = 0.5f * val * (1.f + erff(val * 0.70710678118654752f));
          *(__hip_bfloat16*)&Bs[p_loc * 64 + (((o_loc >> 3) ^ (p_loc & 7)) << 3) + (o_loc & 7)] =
              __float2bfloat16(val);
        }
      }
    int prow = wid * 64 + lane;
    int psw = prow & 7;
    uint4v r8[8];
#pragma unroll
    for (int g = 0; g < 8; g++)
      r8[g] = *(const uint4v*)&Bs[prow * 64 + ((g ^ psw) << 3)];
    unsigned gp = p0 + prow;
    if (EPI == MG_QKV) {
      unsigned bb = gp / PIX, pp = gp - bb * PIX;
      int s = (o0 >= 192) ? 1 : 0;
      int h0 = (o0 - s * 192) >> 5;
      u16* d0 = outT + ((size_t)(bb * NHEADS + h0) * PIX + pp) * 64 + s * 32;
      u16* d1 = outT + ((size_t)(bb * NHEADS + h0 + 1) * PIX + pp) * 64 + s * 32;
      *(uint4v*)(d0) = r8[0]; *(uint4v*)(d0 + 8) = r8[1];
      *(uint4v*)(d0 + 16) = r8[2]; *(uint4v*)(d0 + 24) = r8[3];
      *(uint4v*)(d1) = r8[4]; *(uint4v*)(d1 + 8) = r8[5];
      *(uint4v*)(d1 + 16) = r8[6]; *(uint4v*)(d1 + 24) = r8[7];
    } else if (EPI == MG_PROJ) {
      u16* d = outT + (size_t)gp * CDIM + o0;
#pragma unroll
      for (int g = 0; g < 8; g++) *(uint4v*)(d + g * 8) = r8[g];
    } else {  // GELU -> hT [gp][768]
      u16* d = outT + (size_t)gp * 768 + o0;
#pragma unroll
      for (int g = 0; g < 8; g++) *(uint4v*)(d + g * 8) = r8[g];
    }
  }
}

// ---------------- 7x7 attn conv: 2-img-paired implicit-GEMM MFMA ------------
// Block = (tile, img-pair), 256 thr, 4 waves = Mt x Nt. Per wave acc[2] holds
// img0/img1: each (tap,ks) = 1 A-load (L2) + 2 B ds_reads + 2 MFMAs -> A-traffic
// per pixel halved vs 1-img blocks. LDS: 2 patches granule-major, stride 1608.
#define AGS 1608
#define AIMS (8 * AGS)
__global__ __launch_bounds__(256, 4) void attn_mfma_k(
    const u16* __restrict__ qkT, const u16* __restrict__ wTb2,
    const float* __restrict__ dm_b, const float* __restrict__ rel_bias,
    float* __restrict__ attnL) {
  __shared__ __align__(16) u16 patch[2 * AIMS];  // 51456 B
  int tile = blockIdx.x % 49;
  int pair = blockIdx.x / 49;
  int y0 = (tile / 7) * 8, x0 = (tile % 7) * 8;
  int tid = threadIdx.x;

  // stage 2 patches; g-minor lanes => 128B-coalesced global reads
  for (int idx = tid; idx < 3136; idx += 256) {
    int g = idx & 7;
    int t2 = idx >> 3;
    int im = t2 / 196, lp = t2 - im * 196;
    int row = lp / 14, col = lp - row * 14;
    int gy = y0 - 3 + row, gx = x0 - 3 + col;
    uint4v val = {0u, 0u, 0u, 0u};
    if ((unsigned)gy < 56u && (unsigned)gx < 56u)
      val = *(const uint4v*)(qkT + ((size_t)(pair * 2 + im) * PIX + gy * 56 + gx) * 64 + g * 8);
    *(uint4v*)&patch[im * AIMS + g * AGS + lp * 8] = val;
  }
  __syncthreads();

  int lane = tid & 63, wid = tid >> 6;
  int Mt = wid >> 1, Nt = wid & 1;
  int n = lane & 31, hi = lane >> 5;
  int py = Nt * 4 + (n >> 3), px = n & 7;
  f32x16 acc[2];
#pragma unroll
  for (int im = 0; im < 2; im++)
#pragma unroll
    for (int i = 0; i < 16; i++) acc[im][i] = 0.f;

  const u16* Ab = wTb2 + (size_t)Mt * 100352 + lane * 8;
#pragma unroll
  for (int kh = 0; kh < 7; kh++) {
#pragma unroll
    for (int kw = 0; kw < 7; kw++) {
      int tap = kh * 7 + kw;
      int lp8 = ((py + kh) * 14 + px + kw) * 8;
      const u16* Af = Ab + (size_t)tap * 2048;
#pragma unroll
      for (int ks = 0; ks < 4; ks++) {
        int goff = (ks * 2 + hi) * AGS + lp8;
        bf16x8 a  = __builtin_bit_cast(bf16x8, *(const uint4v*)(Af + ks * 512));
        bf16x8 b0 = __builtin_bit_cast(bf16x8, *(const uint4v*)&patch[goff]);
        bf16x8 b1 = __builtin_bit_cast(bf16x8, *(const uint4v*)&patch[AIMS + goff]);
        acc[0] = __builtin_amdgcn_mfma_f32_32x32x16_bf16(a, b0, acc[0], 0, 0, 0);
        acc[1] = __builtin_amdgcn_mfma_f32_32x32x16_bf16(a, b1, acc[1], 0, 0, 0);
      }
    }
  }

  int pout = (y0 + py) * 56 + x0 + px;
#pragma unroll
  for (int im = 0; im < 2; im++) {
    int img = pair * 2 + im;
    int head = img % NHEADS;
    float* outb = attnL + (size_t)img * KWIN * PIX + pout;
#pragma unroll
    for (int r = 0; r < 16; r++) {
      int ko = Mt * 32 + (r & 3) + 8 * (r >> 2) + 4 * hi;
      if (ko < KWIN)
        outb[(size_t)ko * PIX] = acc[im][r] + dm_b[ko] + rel_bias[ko * NHEADS + head];
    }
  }
}

// ---------------- softmax(49) + v-patch aggregation -> attnoT bf16 ----------
__global__ __launch_bounds__(256) void softagg_k(const float* __restrict__ attnL,
                                                 const float* __restrict__ v,
                                                 u16* __restrict__ attnoT) {
  __shared__ float vp[32][196];
  int img = blockIdx.x / 49, tile = blockIdx.x % 49;
  int y0 = (tile / 7) * 8, x0 = (tile % 7) * 8;
  int tid = threadIdx.x;
  const float* vi = v + (size_t)img * 32 * PIX;
  for (int idx = tid; idx < 32 * 196; idx += 256) {
    int ch = idx / 196, rr = idx - ch * 196;
    int r = rr / 14, cc2 = rr - r * 14;
    int gy = y0 - 3 + r, gx = x0 - 3 + cc2;
    vp[ch][rr] = ((unsigned)gy < 56u && (unsigned)gx < 56u)
                     ? vi[(size_t)ch * PIX + gy * 56 + gx] : 0.f;
  }
  __syncthreads();
  int px = tid & 7, py = (tid >> 3) & 7, cq = tid >> 6;
  int p = (y0 + py) * 56 + x0 + px;
  const float* al = attnL + (size_t)img * KWIN * PIX + p;
  float a[49];
  float m = -1e30f;
#pragma unroll
  for (int k = 0; k < KWIN; k++) { a[k] = al[(size_t)k * PIX]; m = fmaxf(m, a[k]); }
  float s = 0.f;
#pragma unroll
  for (int k = 0; k < KWIN; k++) { a[k] = __expf(a[k] - m); s += a[k]; }
  float inv = 1.f / s;
  int b = img / NHEADS, head = img % NHEADS;
  __hip_bfloat16 ob[8];
#pragma unroll
  for (int c8 = 0; c8 < 8; c8++) {
    int c = cq * 8 + c8;
    float accv = 0.f;
#pragma unroll
    for (int kh = 0; kh < 7; kh++)
#pragma unroll
      for (int kw = 0; kw < 7; kw++)
        accv += a[kh * 7 + kw] * vp[c][(py + kh) * 14 + px + kw];
    ob[c8] = __float2bfloat16(accv * inv);
  }
  *(uint4v*)(attnoT + ((size_t)b * PIX + p) * CDIM + head * 32 + cq * 8) = *(uint4v*)ob;
}

// ---------------- launch ----------------------------------------------------
extern "C" void kernel_launch(void* const* d_in, const int* in_sizes, int n_in,
                              void* d_out, int out_size, void* d_ws, size_t ws_size,
                              hipStream_t stream) {
  const float* x        = (const float*)d_in[0];
  const float* bn_gamma = (const float*)d_in[1];
  const float* bn_beta  = (const float*)d_in[2];
  const float* qkv_w    = (const float*)d_in[3];
  const float* qkv_b    = (const float*)d_in[4];
  const float* dm_w     = (const float*)d_in[5];
  const float* dm_b     = (const float*)d_in[6];
  const float* rel_bias = (const float*)d_in[7];
  const float* proj_w   = (const float*)d_in[8];
  const float* proj_b   = (const float*)d_in[9];
  const float* c1_w     = (const float*)d_in[10];
  const float* c1_b     = (const float*)d_in[11];
  const float* c2_w     = (const float*)d_in[12];
  const float* c2_b     = (const float*)d_in[13];
  float* out = (float*)d_out;
  float* ws  = (float*)d_ws;

  float* stats   = ws;
  float* w_eff   = stats + 384;
  float* b_eff   = w_eff + 110592;
  u16*   pk_qkv  = (u16*)(b_eff + 576);      // 110592 u16
  u16*   pk_proj = pk_qkv + 110592;          // 36864
  u16*   pk_c1   = pk_proj + 36864;          // 147456
  u16*   pk_c2   = pk_c1 + 147456;           // 147456
  u16*   wTb2    = pk_c2 + 147456;           // 200704
  u16*   xT      = wTb2 + 200704;            // 2408448 u16
  u16*   qkT     = xT + 2408448;             // 4816896 u16
  float* vbuf    = (float*)(qkT + 4816896);  // 2408448 f
  float* attnL   = vbuf + 2408448;           // 3687936 f
  u16*   attnoT  = (u16*)(attnL + 3687936);  // 2408448 u16
  float* x1      = (float*)(attnoT + 2408448);  // 2408448 f
  u16*   x1T     = (u16*)(x1 + 2408448);     // 2408448 u16
  u16*   hT      = xT;  // alias: 9633792 u16 over dead xT+qkT+vbuf

  bn_stats_k<<<CDIM, 256, 0, stream>>>(x, stats);
  fold_k<<<576, 192, 0, stream>>>(qkv_w, qkv_b, bn_gamma, bn_beta, stats, w_eff, b_eff);
  wprep_k<<<784, 256, 0, stream>>>(dm_w, (__hip_bfloat16*)wTb2);
  pack_k<<<54, 256, 0, stream>>>(w_eff, pk_qkv, 192, 13824);
  pack_k<<<18, 256, 0, stream>>>(proj_w, pk_proj, 192, 4608);
  pack_k<<<72, 256, 0, stream>>>(c1_w, pk_c1, 192, 18432);
  pack_k<<<72, 256, 0, stream>>>(c2_w, pk_c2, 768, 18432);
  xT_k<<<dim3(BATCH * 49, 6), 256, 0, stream>>>(x, xT);

  mgemm_k<MG_QKV><<<dim3(49, 9), 256, 0, stream>>>(
      xT, pk_qkv, b_eff, vbuf, qkT, nullptr, 192);
  attn_mfma_k<<<588, 256, 0, stream>>>(qkT, wTb2, dm_b, rel_bias, attnL);
  softagg_k<<<NIMG * 49, 256, 0, stream>>>(attnL, vbuf, attnoT);
  mgemm_k<MG_PROJ><<<dim3(49, 3), 256, 0, stream>>>(
      attnoT, pk_proj, proj_b, x1, x1T, x, 192);
  mgemm_k<MG_GELU><<<dim3(49, 12), 256, 0, stream>>>(
      x1T, pk_c1, c1_b, nullptr, hT, nullptr, 192);
  mgemm_k<MG_C2><<<dim3(49, 3), 256, 0, stream>>>(
      hT, pk_c2, c2_b, out, nullptr, x1, 768);
}

// Round 6
// 196.925 us; speedup vs baseline: 1.2765x; 1.0052x over previous
//
#include <hip/hip_runtime.h>
#include <hip/hip_bf16.h>
#include <math.h>

#define CDIM 192
#define NHEADS 6
#define WIN 7
#define KWIN 49
#define BATCH 4
#define PIX 3136      // 56*56
#define NPIX 12544    // BATCH*PIX
#define NIMG 24       // BATCH*NHEADS
#define EPSV 1e-5f

typedef __bf16 bf16x8 __attribute__((ext_vector_type(8)));
typedef float f32x16 __attribute__((ext_vector_type(16)));
typedef unsigned int uint4v __attribute__((ext_vector_type(4)));
typedef unsigned short u16;

// ---------------- BN stats ---------------------------------------------------
__global__ __launch_bounds__(256) void bn_stats_k(const float* __restrict__ x,
                                                  float* __restrict__ stats) {
  int c = blockIdx.x;
  float s = 0.f, q = 0.f;
  for (int n = threadIdx.x; n < BATCH * PIX; n += 256) {
    int b = n / PIX, p = n - b * PIX;
    float v = x[((size_t)b * CDIM + c) * PIX + p];
    s += v; q += v * v;
  }
  __shared__ float rs[256], rq[256];
  rs[threadIdx.x] = s; rq[threadIdx.x] = q;
  __syncthreads();
  for (int st = 128; st > 0; st >>= 1) {
    if (threadIdx.x < st) { rs[threadIdx.x] += rs[threadIdx.x + st]; rq[threadIdx.x] += rq[threadIdx.x + st]; }
    __syncthreads();
  }
  if (threadIdx.x == 0) {
    float mean = rs[0] / (float)(BATCH * PIX);
    float var = rq[0] / (float)(BATCH * PIX) - mean * mean;
    stats[c] = mean;
    stats[CDIM + c] = rsqrtf(var + EPSV);
  }
}

// ---------------- fold BN + q-scale into qkv weights ------------------------
__global__ __launch_bounds__(192) void fold_k(const float* __restrict__ qkv_w,
                                              const float* __restrict__ qkv_b,
                                              const float* __restrict__ gamma,
                                              const float* __restrict__ beta,
                                              const float* __restrict__ stats,
                                              float* __restrict__ w_eff,
                                              float* __restrict__ b_eff) {
  int o = blockIdx.x, c = threadIdx.x;
  float alpha = gamma[c] * stats[CDIM + c];
  float shift = beta[c] - stats[c] * alpha;
  float w = qkv_w[o * CDIM + c];
  float scale = (o < CDIM) ? 0.17677669529663687f : 1.f;
  w_eff[o * CDIM + c] = w * alpha * scale;
  __shared__ float r[CDIM];
  r[c] = w * shift;
  __syncthreads();
  if (c == 0) {
    float s = 0.f;
    for (int i = 0; i < CDIM; i++) s += r[i];
    b_eff[o] = (qkv_b[o] + s) * scale;
  }
}

// ---------------- pack dm_w (attn conv weights) frag-major ------------------
__global__ __launch_bounds__(256) void wprep_k(const float* __restrict__ dm_w,
                                               __hip_bfloat16* __restrict__ wTb2) {
  int idx = blockIdx.x * 256 + threadIdx.x;
  if (idx >= 200704) return;
  int e = idx & 7;
  int tmp = idx >> 3;
  int lane = tmp & 63; tmp >>= 6;
  int ch = tmp & 3; tmp >>= 2;
  int tap = tmp % 49, Mt = tmp / 49;
  int ko = Mt * 32 + (lane & 31);
  int ci = ch * 16 + (lane >> 5) * 8 + e;
  float v = (ko < KWIN) ? dm_w[(size_t)ko * 3136 + ci * 49 + tap] : 0.f;
  wTb2[idx] = __float2bfloat16(v);
}

// ---------------- generic GEMM weight pack: W[Cout][Cin] -> frag-major ------
__global__ __launch_bounds__(256) void pack_k(const float* __restrict__ W,
                                              u16* __restrict__ out,
                                              int Cin, int total8) {
  int t = blockIdx.x * 256 + threadIdx.x;
  if (t >= total8) return;
  int lane = t & 63, rest = t >> 6;
  int nK = Cin >> 4;
  int kk = rest % nK, mtg = rest / nK;
  int o = mtg * 32 + (lane & 31), c = kk * 16 + (lane >> 5) * 8;
  const float* src = W + (size_t)o * Cin + c;
  __hip_bfloat16 tmp[8];
#pragma unroll
  for (int e = 0; e < 8; e++) tmp[e] = __float2bfloat16(src[e]);
  *(uint4v*)(out + (size_t)t * 8) = *(uint4v*)tmp;
}

// ---------------- x [b][c][p] fp32 -> xT [b*p][192] bf16 --------------------
__global__ __launch_bounds__(256) void xT_k(const float* __restrict__ x,
                                            u16* __restrict__ xT) {
  __shared__ float Ls[64][33];
  int bb = blockIdx.x / 49;
  int p0 = (blockIdx.x % 49) * 64;
  int c0 = blockIdx.y * 32;
  int tid = threadIdx.x;
  int j = tid & 63;
#pragma unroll
  for (int it = 0; it < 8; it++) {
    int c = it * 4 + (tid >> 6);
    Ls[j][c] = x[((size_t)bb * CDIM + c0 + c) * PIX + p0 + j];
  }
  __syncthreads();
  int jr = tid >> 2, t = tid & 3;
  __hip_bfloat16 tmp[8];
#pragma unroll
  for (int u = 0; u < 8; u++) tmp[u] = __float2bfloat16(Ls[jr][t * 8 + u]);
  *(uint4v*)(xT + (size_t)(bb * PIX + p0 + jr) * CDIM + c0 + t * 8) = *(uint4v*)tmp;
}

// ---------------- MFMA GEMM: Y[o][gp] = sum_c W[o][c] * Bm[gp][c] -----------
#define MG_QKV 0
#define MG_PROJ 1
#define MG_GELU 2
#define MG_C2 3
#define MGS 2056

template <int EPI>
__global__ __launch_bounds__(256) void mgemm_k(
    const u16* __restrict__ Bm, const u16* __restrict__ Apk,
    const float* __restrict__ bias,
    float* __restrict__ outF, u16* __restrict__ outT,
    const float* __restrict__ extra, int Cin) {
  __shared__ __align__(16) u16 Bs[8 * MGS];  // 32.9 KB
  int tid = threadIdx.x;
  int lane = tid & 63, wid = tid >> 6;
  int hi = lane >> 5, ln31 = lane & 31;
  int p0 = blockIdx.x * 256;
  int o0 = blockIdx.y * 64;
  int nK = Cin >> 4;
  f32x16 acc[2][2];
#pragma unroll
  for (int mt = 0; mt < 2; mt++)
#pragma unroll
    for (int nt = 0; nt < 2; nt++)
#pragma unroll
      for (int i = 0; i < 16; i++) acc[mt][nt][i] = 0.f;

  for (int cc = 0; cc < Cin; cc += 64) {
#pragma unroll
    for (int i = 0; i < 8; i++) {
      int idx = i * 256 + tid;
      int g = idx & 7, p = idx >> 3;
      uint4v v = *(const uint4v*)(Bm + (size_t)(p0 + p) * Cin + cc + g * 8);
      *(uint4v*)&Bs[g * MGS + p * 8] = v;
    }
    __syncthreads();
    const u16* Ab = Apk + ((size_t)(o0 >> 5) * nK + (cc >> 4)) * 512 + lane * 8;
    int pA = wid * 64 + ln31;
    int pB = pA + 32;
#pragma unroll
    for (int ks = 0; ks < 4; ks++) {
      int g = ks * 2 + hi;
      bf16x8 b0 = *(const bf16x8*)&Bs[g * MGS + pA * 8];
      bf16x8 b1 = *(const bf16x8*)&Bs[g * MGS + pB * 8];
      bf16x8 a0 = *(const bf16x8*)(Ab + ks * 512);
      bf16x8 a1 = *(const bf16x8*)(Ab + (nK + ks) * 512);
      acc[0][0] = __builtin_amdgcn_mfma_f32_32x32x16_bf16(a0, b0, acc[0][0], 0, 0, 0);
      acc[0][1] = __builtin_amdgcn_mfma_f32_32x32x16_bf16(a0, b1, acc[0][1], 0, 0, 0);
      acc[1][0] = __builtin_amdgcn_mfma_f32_32x32x16_bf16(a1, b0, acc[1][0], 0, 0, 0);
      acc[1][1] = __builtin_amdgcn_mfma_f32_32x32x16_bf16(a1, b1, acc[1][1], 0, 0, 0);
    }
    __syncthreads();
  }

  // ---- epilogue ----
  if (EPI == MG_C2 || (EPI == MG_QKV && o0 >= 384)) {
#pragma unroll
    for (int mt = 0; mt < 2; mt++)
#pragma unroll
      for (int r = 0; r < 16; r++) {
        int o = o0 + mt * 32 + (r & 3) + 8 * (r >> 2) + 4 * hi;
        float bv = bias[o];
#pragma unroll
        for (int nt = 0; nt < 2; nt++) {
          unsigned gp = p0 + wid * 64 + nt * 32 + ln31;
          unsigned bb = gp / PIX, pp = gp - bb * PIX;
          if (EPI == MG_C2) {
            size_t oi = ((size_t)bb * CDIM + o) * PIX + pp;
            outF[oi] = acc[mt][nt][r] + bv + extra[oi];
          } else {  // v
            int ch = o - 384;
            outF[((size_t)(bb * NHEADS + (ch >> 5)) * 32 + (ch & 31)) * PIX + pp] =
                acc[mt][nt][r] + bv;
          }
        }
      }
  } else {
    // bf16-transposed output via wave-local LDS transpose (Bs reused as scratch)
#pragma unroll
    for (int mt = 0; mt < 2; mt++)
#pragma unroll
      for (int r = 0; r < 16; r++) {
        int o_loc = mt * 32 + (r & 3) + 8 * (r >> 2) + 4 * hi;
        int o = o0 + o_loc;
        float bv = bias[o];
#pragma unroll
        for (int nt = 0; nt < 2; nt++) {
          int p_loc = wid * 64 + nt * 32 + ln31;
          float val = acc[mt][nt][r] + bv;
          if (EPI == MG_PROJ) {
            unsigned gp = p0 + p_loc;
            unsigned bb = gp / PIX, pp = gp - bb * PIX;
            size_t oi = ((size_t)bb * CDIM + o) * PIX + pp;
            val += extra[oi];
            outF[oi] = val;
          }
          if (EPI == MG_GELU)
            val = 0.5f * val * (1.f + erff(val * 0.70710678118654752f));
          *(__hip_bfloat16*)&Bs[p_loc * 64 + (((o_loc >> 3) ^ (p_loc & 7)) << 3) + (o_loc & 7)] =
              __float2bfloat16(val);
        }
      }
    int prow = wid * 64 + lane;
    int psw = prow & 7;
    uint4v r8[8];
#pragma unroll
    for (int g = 0; g < 8; g++)
      r8[g] = *(const uint4v*)&Bs[prow * 64 + ((g ^ psw) << 3)];
    unsigned gp = p0 + prow;
    if (EPI == MG_QKV) {
      unsigned bb = gp / PIX, pp = gp - bb * PIX;
      int s = (o0 >= 192) ? 1 : 0;
      int h0 = (o0 - s * 192) >> 5;
      u16* d0 = outT + ((size_t)(bb * NHEADS + h0) * PIX + pp) * 64 + s * 32;
      u16* d1 = outT + ((size_t)(bb * NHEADS + h0 + 1) * PIX + pp) * 64 + s * 32;
      *(uint4v*)(d0) = r8[0]; *(uint4v*)(d0 + 8) = r8[1];
      *(uint4v*)(d0 + 16) = r8[2]; *(uint4v*)(d0 + 24) = r8[3];
      *(uint4v*)(d1) = r8[4]; *(uint4v*)(d1 + 8) = r8[5];
      *(uint4v*)(d1 + 16) = r8[6]; *(uint4v*)(d1 + 24) = r8[7];
    } else if (EPI == MG_PROJ) {
      u16* d = outT + (size_t)gp * CDIM + o0;
#pragma unroll
      for (int g = 0; g < 8; g++) *(uint4v*)(d + g * 8) = r8[g];
    } else {  // GELU -> hT [gp][768]
      u16* d = outT + (size_t)gp * 768 + o0;
#pragma unroll
      for (int g = 0; g < 8; g++) *(uint4v*)(d + g * 8) = r8[g];
    }
  }
}

// ---------------- 7x7 attn conv: 2-img + Mt-in-acc + Ks-split MFMA ----------
// Block = (tile, img-pair), 4 waves = (Nt, s) where s = K-half (ci 0-31/32-63).
// Per (tap,ks): 2 A-loads + 2 B ds_reads + 4 MFMAs (im x Mt in acc) -> B-reads
// at the structural floor (0.5 per MFMA). Ks-split partials combined via a
// symmetric LDS reduction (wave writes partial of the OTHER img, reads its
// partner's partial of its OWN img), each wave then owns one img's epilogue.
#define AGS 1608
#define AIMS (8 * AGS)
__global__ __launch_bounds__(256, 3) void attn_mfma_k(
    const u16* __restrict__ qkT, const u16* __restrict__ wTb2,
    const float* __restrict__ dm_b, const float* __restrict__ rel_bias,
    float* __restrict__ attnL) {
  __shared__ __align__(16) u16 patch[2 * AIMS];  // 51456 B
  int tile = blockIdx.x % 49;
  int pair = blockIdx.x / 49;
  int y0 = (tile / 7) * 8, x0 = (tile % 7) * 8;
  int tid = threadIdx.x;

  for (int idx = tid; idx < 3136; idx += 256) {
    int g = idx & 7;
    int t2 = idx >> 3;
    int im = t2 / 196, lp = t2 - im * 196;
    int row = lp / 14, col = lp - row * 14;
    int gy = y0 - 3 + row, gx = x0 - 3 + col;
    uint4v val = {0u, 0u, 0u, 0u};
    if ((unsigned)gy < 56u && (unsigned)gx < 56u)
      val = *(const uint4v*)(qkT + ((size_t)(pair * 2 + im) * PIX + gy * 56 + gx) * 64 + g * 8);
    *(uint4v*)&patch[im * AIMS + g * AGS + lp * 8] = val;
  }
  __syncthreads();

  int lane = tid & 63, wid = tid >> 6;
  int Nt = wid & 1, s = wid >> 1;       // s = K-half
  int n = lane & 31, hi = lane >> 5;
  int py = Nt * 4 + (n >> 3), px = n & 7;
  f32x16 accA[2], accB[2];              // accA = im0, accB = im1; index = Mt
#pragma unroll
  for (int mt = 0; mt < 2; mt++)
#pragma unroll
    for (int i = 0; i < 16; i++) { accA[mt][i] = 0.f; accB[mt][i] = 0.f; }

  const u16* Ab = wTb2 + lane * 8;
  int s2 = s * 2;
#pragma unroll
  for (int kh = 0; kh < 7; kh++) {
#pragma unroll
    for (int kw = 0; kw < 7; kw++) {
      int tap = kh * 7 + kw;
      int lp8 = ((py + kh) * 14 + px + kw) * 8;
      const u16* Af = Ab + (size_t)tap * 2048;
#pragma unroll
      for (int kk = 0; kk < 2; kk++) {
        int ks = s2 + kk;
        int goff = (ks * 2 + hi) * AGS + lp8;
        bf16x8 a0 = __builtin_bit_cast(bf16x8, *(const uint4v*)(Af + ks * 512));
        bf16x8 a1 = __builtin_bit_cast(bf16x8, *(const uint4v*)(Af + 100352 + ks * 512));
        bf16x8 b0 = __builtin_bit_cast(bf16x8, *(const uint4v*)&patch[goff]);
        bf16x8 b1 = __builtin_bit_cast(bf16x8, *(const uint4v*)&patch[AIMS + goff]);
        accA[0] = __builtin_amdgcn_mfma_f32_32x32x16_bf16(a0, b0, accA[0], 0, 0, 0);
        accA[1] = __builtin_amdgcn_mfma_f32_32x32x16_bf16(a1, b0, accA[1], 0, 0, 0);
        accB[0] = __builtin_amdgcn_mfma_f32_32x32x16_bf16(a0, b1, accB[0], 0, 0, 0);
        accB[1] = __builtin_amdgcn_mfma_f32_32x32x16_bf16(a1, b1, accB[1], 0, 0, 0);
      }
    }
  }

  // ---- Ks-split reduction: write partial of OTHER img, read partner's ------
  __syncthreads();
  float* rbuf = (float*)patch;  // 4 waves x 8 rg x 64 lanes x 16B = 32 KB
#pragma unroll
  for (int mt = 0; mt < 2; mt++)
#pragma unroll
    for (int q = 0; q < 4; q++) {
      float4 v4;
      if (s == 0) {
        v4 = make_float4(accB[mt][q * 4], accB[mt][q * 4 + 1],
                         accB[mt][q * 4 + 2], accB[mt][q * 4 + 3]);
      } else {
        v4 = make_float4(accA[mt][q * 4], accA[mt][q * 4 + 1],
                         accA[mt][q * 4 + 2], accA[mt][q * 4 + 3]);
      }
      *(float4*)&rbuf[(((wid * 8) + mt * 4 + q) * 64 + lane) * 4] = v4;
    }
  __syncthreads();
  int partner = wid ^ 2;
#pragma unroll
  for (int mt = 0; mt < 2; mt++)
#pragma unroll
    for (int q = 0; q < 4; q++) {
      float4 v4 = *(const float4*)&rbuf[(((partner * 8) + mt * 4 + q) * 64 + lane) * 4];
      if (s == 0) {
        accA[mt][q * 4] += v4.x; accA[mt][q * 4 + 1] += v4.y;
        accA[mt][q * 4 + 2] += v4.z; accA[mt][q * 4 + 3] += v4.w;
      } else {
        accB[mt][q * 4] += v4.x; accB[mt][q * 4 + 1] += v4.y;
        accB[mt][q * 4 + 2] += v4.z; accB[mt][q * 4 + 3] += v4.w;
      }
    }

  // ---- epilogue: wave s owns img = pair*2 + s ------------------------------
  int img = pair * 2 + s;
  int head = img % NHEADS;
  int pout = (y0 + py) * 56 + x0 + px;
  float* outb = attnL + (size_t)img * KWIN * PIX + pout;
#pragma unroll
  for (int mt = 0; mt < 2; mt++)
#pragma unroll
    for (int r = 0; r < 16; r++) {
      int ko = mt * 32 + (r & 3) + 8 * (r >> 2) + 4 * hi;
      if (ko < KWIN) {
        float v = (s == 0) ? accA[mt][r] : accB[mt][r];
        outb[(size_t)ko * PIX] = v + dm_b[ko] + rel_bias[ko * NHEADS + head];
      }
    }
}

// ---------------- softmax(49) + v-patch aggregation -> attnoT bf16 ----------
__global__ __launch_bounds__(256) void softagg_k(const float* __restrict__ attnL,
                                                 const float* __restrict__ v,
                                                 u16* __restrict__ attnoT) {
  __shared__ float vp[32][196];
  int img = blockIdx.x / 49, tile = blockIdx.x % 49;
  int y0 = (tile / 7) * 8, x0 = (tile % 7) * 8;
  int tid = threadIdx.x;
  const float* vi = v + (size_t)img * 32 * PIX;
  for (int idx = tid; idx < 32 * 196; idx += 256) {
    int ch = idx / 196, rr = idx - ch * 196;
    int r = rr / 14, cc2 = rr - r * 14;
    int gy = y0 - 3 + r, gx = x0 - 3 + cc2;
    vp[ch][rr] = ((unsigned)gy < 56u && (unsigned)gx < 56u)
                     ? vi[(size_t)ch * PIX + gy * 56 + gx] : 0.f;
  }
  __syncthreads();
  int px = tid & 7, py = (tid >> 3) & 7, cq = tid >> 6;
  int p = (y0 + py) * 56 + x0 + px;
  const float* al = attnL + (size_t)img * KWIN * PIX + p;
  float a[49];
  float m = -1e30f;
#pragma unroll
  for (int k = 0; k < KWIN; k++) { a[k] = al[(size_t)k * PIX]; m = fmaxf(m, a[k]); }
  float s = 0.f;
#pragma unroll
  for (int k = 0; k < KWIN; k++) { a[k] = __expf(a[k] - m); s += a[k]; }
  float inv = 1.f / s;
  int b = img / NHEADS, head = img % NHEADS;
  __hip_bfloat16 ob[8];
#pragma unroll
  for (int c8 = 0; c8 < 8; c8++) {
    int c = cq * 8 + c8;
    float accv = 0.f;
#pragma unroll
    for (int kh = 0; kh < 7; kh++)
#pragma unroll
      for (int kw = 0; kw < 7; kw++)
        accv += a[kh * 7 + kw] * vp[c][(py + kh) * 14 + px + kw];
    ob[c8] = __float2bfloat16(accv * inv);
  }
  *(uint4v*)(attnoT + ((size_t)b * PIX + p) * CDIM + head * 32 + cq * 8) = *(uint4v*)ob;
}

// ---------------- launch ----------------------------------------------------
extern "C" void kernel_launch(void* const* d_in, const int* in_sizes, int n_in,
                              void* d_out, int out_size, void* d_ws, size_t ws_size,
                              hipStream_t stream) {
  const float* x        = (const float*)d_in[0];
  const float* bn_gamma = (const float*)d_in[1];
  const float* bn_beta  = (const float*)d_in[2];
  const float* qkv_w    = (const float*)d_in[3];
  const float* qkv_b    = (const float*)d_in[4];
  const float* dm_w     = (const float*)d_in[5];
  const float* dm_b     = (const float*)d_in[6];
  const float* rel_bias = (const float*)d_in[7];
  const float* proj_w   = (const float*)d_in[8];
  const float* proj_b   = (const float*)d_in[9];
  const float* c1_w     = (const float*)d_in[10];
  const float* c1_b     = (const float*)d_in[11];
  const float* c2_w     = (const float*)d_in[12];
  const float* c2_b     = (const float*)d_in[13];
  float* out = (float*)d_out;
  float* ws  = (float*)d_ws;

  float* stats   = ws;
  float* w_eff   = stats + 384;
  float* b_eff   = w_eff + 110592;
  u16*   pk_qkv  = (u16*)(b_eff + 576);      // 110592 u16
  u16*   pk_proj = pk_qkv + 110592;          // 36864
  u16*   pk_c1   = pk_proj + 36864;          // 147456
  u16*   pk_c2   = pk_c1 + 147456;           // 147456
  u16*   wTb2    = pk_c2 + 147456;           // 200704
  u16*   xT      = wTb2 + 200704;            // 2408448 u16
  u16*   qkT     = xT + 2408448;             // 4816896 u16
  float* vbuf    = (float*)(qkT + 4816896);  // 2408448 f
  float* attnL   = vbuf + 2408448;           // 3687936 f
  u16*   attnoT  = (u16*)(attnL + 3687936);  // 2408448 u16
  float* x1      = (float*)(attnoT + 2408448);  // 2408448 f
  u16*   x1T     = (u16*)(x1 + 2408448);     // 2408448 u16
  u16*   hT      = xT;  // alias: 9633792 u16 over dead xT+qkT+vbuf

  bn_stats_k<<<CDIM, 256, 0, stream>>>(x, stats);
  fold_k<<<576, 192, 0, stream>>>(qkv_w, qkv_b, bn_gamma, bn_beta, stats, w_eff, b_eff);
  wprep_k<<<784, 256, 0, stream>>>(dm_w, (__hip_bfloat16*)wTb2);
  pack_k<<<54, 256, 0, stream>>>(w_eff, pk_qkv, 192, 13824);
  pack_k<<<18, 256, 0, stream>>>(proj_w, pk_proj, 192, 4608);
  pack_k<<<72, 256, 0, stream>>>(c1_w, pk_c1, 192, 18432);
  pack_k<<<72, 256, 0, stream>>>(c2_w, pk_c2, 768, 18432);
  xT_k<<<dim3(BATCH * 49, 6), 256, 0, stream>>>(x, xT);

  mgemm_k<MG_QKV><<<dim3(49, 9), 256, 0, stream>>>(
      xT, pk_qkv, b_eff, vbuf, qkT, nullptr, 192);
  attn_mfma_k<<<588, 256, 0, stream>>>(qkT, wTb2, dm_b, rel_bias, attnL);
  softagg_k<<<NIMG * 49, 256, 0, stream>>>(attnL, vbuf, attnoT);
  mgemm_k<MG_PROJ><<<dim3(49, 3), 256, 0, stream>>>(
      attnoT, pk_proj, proj_b, x1, x1T, x, 192);
  mgemm_k<MG_GELU><<<dim3(49, 12), 256, 0, stream>>>(
      x1T, pk_c1, c1_b, nullptr, hT, nullptr, 192);
  mgemm_k<MG_C2><<<dim3(49, 3), 256, 0, stream>>>(
      hT, pk_c2, c2_b, out, nullptr, x1, 768);
}